// Round 4
// baseline (130.654 us; speedup 1.0000x reference)
//
#include <hip/hip_runtime.h>

// SNN forward, two kernels.
// GEMM kernel: persistent blocks, 16-row tiles (16*3136 B = 49 KiB = exactly
// 49 aligned 1-KiB spans; tile base always 1-KiB aligned). x staged
// global->LDS via global_load_lds with IDENTITY addressing: every DMA
// instruction reads a contiguous, 1024-aligned 1 KiB (max HBM burst
// efficiency); dest = linear LDS image of the 16 rows.
// Waves split f-chunks (not rows): W-LDS reads are 4-row broadcast-amortized.
// LDS row stride 784 floats => b128 reads hit the 8-span/bank floor (rows in
// one instruction differ by 4 -> 3136 B stride == 0 mod 32 banks -> even
// coverage, no excess conflict). 16-lane reduction via DPP on the VALU pipe.
// Double-buffered tiles, per-wave counted vmcnt, RAW s_barrier (not
// __syncthreads -- which would emit s_waitcnt vmcnt(0) and drain the
// prefetch pipeline at every tile boundary).

#define T_STEPS 64
#define BATCH   2048
#define FEAT    784
#define OUT_N   10
#define ROWS_TOTAL (T_STEPS * BATCH)          // 131072
#define TILE_ROWS  16
#define TILE_FLTS  (TILE_ROWS * FEAT)         // 12544 floats = 49 KiB
#define NTILES     (ROWS_TOTAL / TILE_ROWS)   // 8192
#define NBLOCKS    512
#define TPB        (NTILES / NBLOCKS)         // 16 tiles per block
#define W_FLOATS   (OUT_N * FEAT)             // 7840
#define PART_FLTS  (4 * TILE_ROWS * OUT_N)    // 640
#define SMEM_BYTES ((W_FLOATS + 2 * TILE_FLTS + PART_FLTS) * 4)  // 134272 B

typedef __attribute__((address_space(1))) const void GV;
typedef __attribute__((address_space(3))) void LV;

__device__ __forceinline__ void gld16(const float* src, float* dst) {
    __builtin_amdgcn_global_load_lds((GV*)src, (LV*)dst, 16, 0, 0);
}

template <int CTRL>
__device__ __forceinline__ float dpp_mov(float v) {
    return __int_as_float(
        __builtin_amdgcn_update_dpp(0, __float_as_int(v), CTRL, 0xF, 0xF, true));
}
// sum over each aligned 16-lane group: xor1, xor2, xor7, xor15 generate Z16
__device__ __forceinline__ float red16(float v) {
    v += dpp_mov<0xB1>(v);    // quad_perm [1,0,3,2]  = xor 1
    v += dpp_mov<0x4E>(v);    // quad_perm [2,3,0,1]  = xor 2
    v += dpp_mov<0x141>(v);   // row_half_mirror      = xor 7
    v += dpp_mov<0x140>(v);   // row_mirror           = xor 15
    return v;
}

__global__ __launch_bounds__(256)
void snn_gemm(const float* __restrict__ x, const float* __restrict__ W,
              const float* __restrict__ bias, float* __restrict__ C) {
    extern __shared__ float smem[];
    float* Wl   = smem;                       // [10][784]
    float* xb0  = smem + W_FLOATS;            // tile buffer 0
    float* xb1  = xb0 + TILE_FLTS;            // tile buffer 1
    float* part = xb1 + TILE_FLTS;            // [4 waves][16 rows][10]

    const int tid = threadIdx.x;
    const int w   = tid >> 6;
    const int ln  = tid & 63;
    const int l16 = ln & 15;
    const int r   = ln >> 4;

    for (int i = tid; i < W_FLOATS; i += 256) Wl[i] = W[i];
    __syncthreads();   // full drain OK here: nothing prefetched yet

    const float* xblk = x + (size_t)blockIdx.x * TPB * TILE_FLTS;

    // stage tile t: wave w issues spans k = 4i+w (12 each); wave 0 also k=48.
    auto stage = [&](int t, float* buf) {
        const float* src = xblk + (size_t)t * TILE_FLTS + ln * 4;
#pragma unroll
        for (int i = 0; i < 12; ++i) {
            const int k = 4 * i + w;
            gld16(src + k * 256, buf + k * 256);
        }
        if (w == 0) gld16(src + 48 * 256, buf + 48 * 256);
    };

    stage(0, xb0);

#pragma unroll 1
    for (int t = 0; t < TPB; ++t) {
        float* buf = (t & 1) ? xb1 : xb0;
        if (t + 1 < TPB) {
            stage(t + 1, (t & 1) ? xb0 : xb1);
            // leave only the newest stage's loads outstanding -> tile t landed,
            // tile t+1 stays in flight ACROSS the barrier
            if (w == 0) asm volatile("s_waitcnt vmcnt(13)" ::: "memory");
            else        asm volatile("s_waitcnt vmcnt(12)" ::: "memory");
        } else {
            asm volatile("s_waitcnt vmcnt(0)" ::: "memory");
        }
        __builtin_amdgcn_s_barrier();   // raw: no compiler vmcnt(0) drain

        float acc[4][OUT_N];
#pragma unroll
        for (int g = 0; g < 4; ++g)
#pragma unroll
            for (int o = 0; o < OUT_N; ++o) acc[g][o] = 0.0f;

        // wave w handles f-chunks {w, w+4, w+8} (64 floats each)
#pragma unroll
        for (int cc = 0; cc < 3; ++cc) {
            const int c = w + 4 * cc;
            float4 xf[4];
#pragma unroll
            for (int g = 0; g < 4; ++g)
                xf[g] = *(const float4*)&buf[(4 * r + g) * FEAT + c * 64 + l16 * 4];
#pragma unroll
            for (int o = 0; o < OUT_N; ++o) {
                const float4 wf = *(const float4*)&Wl[o * FEAT + c * 64 + l16 * 4];
#pragma unroll
                for (int g = 0; g < 4; ++g) {
                    acc[g][o] = fmaf(xf[g].x, wf.x, acc[g][o]);
                    acc[g][o] = fmaf(xf[g].y, wf.y, acc[g][o]);
                    acc[g][o] = fmaf(xf[g].z, wf.z, acc[g][o]);
                    acc[g][o] = fmaf(xf[g].w, wf.w, acc[g][o]);
                }
            }
        }
        // tail feats 768..783: wave 3, lanes l16 < 4
        if (w == 3 && l16 < 4) {
#pragma unroll
            for (int g = 0; g < 4; ++g) {
                const float4 xt = *(const float4*)&buf[(4 * r + g) * FEAT + 768 + l16 * 4];
#pragma unroll
                for (int o = 0; o < OUT_N; ++o) {
                    const float4 wf = *(const float4*)&Wl[o * FEAT + 768 + l16 * 4];
                    acc[g][o] = fmaf(xt.x, wf.x, acc[g][o]);
                    acc[g][o] = fmaf(xt.y, wf.y, acc[g][o]);
                    acc[g][o] = fmaf(xt.z, wf.z, acc[g][o]);
                    acc[g][o] = fmaf(xt.w, wf.w, acc[g][o]);
                }
            }
        }

        // reduce over the 16 f-lanes on the VALU pipe (DPP)
#pragma unroll
        for (int g = 0; g < 4; ++g)
#pragma unroll
            for (int o = 0; o < OUT_N; ++o) acc[g][o] = red16(acc[g][o]);

        if (l16 == 0) {
#pragma unroll
            for (int g = 0; g < 4; ++g) {
                float* p = &part[(w * TILE_ROWS + 4 * r + g) * OUT_N];
                *(float4*)&p[0] = make_float4(acc[g][0], acc[g][1], acc[g][2], acc[g][3]);
                *(float4*)&p[4] = make_float4(acc[g][4], acc[g][5], acc[g][6], acc[g][7]);
                *(float2*)&p[8] = make_float2(acc[g][8], acc[g][9]);
            }
        }
        asm volatile("s_waitcnt lgkmcnt(0)" ::: "memory");  // part writes visible
        __builtin_amdgcn_s_barrier();

        if (tid < TILE_ROWS * OUT_N) {
            const int o = tid % OUT_N;
            const float s = part[tid] + part[160 + tid] + part[320 + tid] +
                            part[480 + tid] + bias[o];
            C[(size_t)(blockIdx.x * TPB + t) * (TILE_ROWS * OUT_N) + tid] = s;
        }
        // part reads complete (lgkmcnt waited for the C-store data dep) before
        // this thread reaches the next iteration's barrier; next part-write
        // happens only after that barrier -> no WAR race.
    }
}

// Phase 2: one thread per (b, o); IF-neuron scan over t.
__global__ __launch_bounds__(256)
void snn_scan(const float* __restrict__ C, float* __restrict__ out) {
    const int idx = blockIdx.x * 256 + threadIdx.x;   // b*OUT_N + o
    if (idx >= BATCH * OUT_N) return;
    float v = 0.0f;
    float cnt = 0.0f;
#pragma unroll
    for (int t = 0; t < T_STEPS; ++t) {
        v += C[(size_t)t * BATCH * OUT_N + idx];
        if (v >= 1.0f) { cnt += 1.0f; v = 0.0f; }
    }
    out[idx] = cnt * (1.0f / 64.0f);
}

extern "C" void kernel_launch(void* const* d_in, const int* in_sizes, int n_in,
                              void* d_out, int out_size, void* d_ws, size_t ws_size,
                              hipStream_t stream) {
    const float* x    = (const float*)d_in[0];   // [64, 2048, 784] f32
    const float* W    = (const float*)d_in[1];   // [10, 784] f32
    const float* bias = (const float*)d_in[2];   // [10] f32
    float* out = (float*)d_out;                  // [2048, 10] f32
    float* C   = (float*)d_ws;                   // [131072, 10] f32 scratch

    hipFuncSetAttribute(reinterpret_cast<const void*>(snn_gemm),
                        hipFuncAttributeMaxDynamicSharedMemorySize, SMEM_BYTES);

    snn_gemm<<<dim3(NBLOCKS), dim3(256), SMEM_BYTES, stream>>>(x, W, bias, C);
    snn_scan<<<dim3((BATCH * OUT_N + 255) / 256), dim3(256), 0, stream>>>(C, out);
}

// Round 5
// 88.298 us; speedup vs baseline: 1.4797x; 1.4797x over previous
//
#include <hip/hip_runtime.h>

// SNN forward, two kernels — round-1 structure (best so far) + three safe fixes:
//  1. rolled chunk loop (#pragma unroll 2) with explicit next-chunk register
//     prefetch: compact I$ footprint, guaranteed load/FMA overlap (the full
//     unroll emitted ~18 KB of hot code).
//  2. 16-lane reduction via DPP butterflies (pure VALU) instead of 160
//     ds_bpermute ops per wave (validated bit-exact on-device in round 4).
//  3. packed float2 C-stores + float4 cooperative W staging.
// GEMM: block = 64 rows, wave = 16 rows (4 slots x 4 rows), 16 f-lanes each.
// W (31 KB) in LDS, broadcast-read. x read direct-to-VGPR, coalesced 256 B
// segments. 2048 blocks, ~5 blocks/CU (LDS-capped), ~20 waves/CU.

#define T_STEPS 64
#define BATCH   2048
#define FEAT    784
#define OUT_N   10
#define ROWS    (T_STEPS * BATCH)   // 131072

typedef __attribute__((ext_vector_type(4))) float f4;
typedef __attribute__((ext_vector_type(2))) float f2;

template <int CTRL>
__device__ __forceinline__ float dpp_mov(float v) {
    return __int_as_float(
        __builtin_amdgcn_update_dpp(0, __float_as_int(v), CTRL, 0xF, 0xF, true));
}
// sum over each aligned 16-lane group: xor1, xor2, xor7(half_mirror),
// xor15(mirror) generate the group — verified bit-exact on gfx950 (round 4).
__device__ __forceinline__ float red16(float v) {
    v += dpp_mov<0xB1>(v);    // quad_perm [1,0,3,2]  = xor 1
    v += dpp_mov<0x4E>(v);    // quad_perm [2,3,0,1]  = xor 2
    v += dpp_mov<0x141>(v);   // row_half_mirror      = xor 7
    v += dpp_mov<0x140>(v);   // row_mirror           = xor 15
    return v;
}

__global__ __launch_bounds__(256)
void snn_gemm(const float* __restrict__ x, const float* __restrict__ W,
              const float* __restrict__ bias, float* __restrict__ C) {
    __shared__ float Wl[OUT_N * FEAT];   // 31360 B

    {   // cooperative W load, vectorized (1960 float4s)
        const f4* Wg = (const f4*)W;
        f4* Ws = (f4*)Wl;
        for (int i = threadIdx.x; i < OUT_N * FEAT / 4; i += 256) Ws[i] = Wg[i];
    }
    __syncthreads();

    const int tid  = threadIdx.x;
    const int w    = tid >> 6;
    const int ln   = tid & 63;
    const int l16  = ln & 15;        // feature slice
    const int r    = ln >> 4;        // row slot
    const long row0 = (long)blockIdx.x * 64 + w * 16 + r * 4;

    const float* xbase = x + (size_t)row0 * FEAT + 4 * l16;

    float acc[4][OUT_N];
#pragma unroll
    for (int g = 0; g < 4; ++g)
#pragma unroll
        for (int o = 0; o < OUT_N; ++o) acc[g][o] = 0.0f;

    // prefetch chunk 0
    f4 cur[4];
#pragma unroll
    for (int g = 0; g < 4; ++g)
        cur[g] = *(const f4*)(xbase + (size_t)g * FEAT);

#pragma unroll 2
    for (int c = 0; c < 12; ++c) {
        f4 nxt[4];
        if (c < 11) {
#pragma unroll
            for (int g = 0; g < 4; ++g)
                nxt[g] = *(const f4*)(xbase + (size_t)g * FEAT + (c + 1) * 64);
        }
#pragma unroll
        for (int o = 0; o < OUT_N; ++o) {
            const f4 wf = *(const f4*)&Wl[o * FEAT + c * 64 + l16 * 4];
#pragma unroll
            for (int g = 0; g < 4; ++g) {
                acc[g][o] = fmaf(cur[g].x, wf.x, acc[g][o]);
                acc[g][o] = fmaf(cur[g].y, wf.y, acc[g][o]);
                acc[g][o] = fmaf(cur[g].z, wf.z, acc[g][o]);
                acc[g][o] = fmaf(cur[g].w, wf.w, acc[g][o]);
            }
        }
        if (c < 11) {
#pragma unroll
            for (int g = 0; g < 4; ++g) cur[g] = nxt[g];
        }
    }

    // tail feats 768..783: lanes l16 < 4 add 4 floats each
    if (l16 < 4) {
#pragma unroll
        for (int g = 0; g < 4; ++g) {
            const f4 xt = *(const f4*)(xbase + (size_t)g * FEAT + 768);
#pragma unroll
            for (int o = 0; o < OUT_N; ++o) {
                const f4 wf = *(const f4*)&Wl[o * FEAT + 768 + l16 * 4];
                acc[g][o] = fmaf(xt.x, wf.x, acc[g][o]);
                acc[g][o] = fmaf(xt.y, wf.y, acc[g][o]);
                acc[g][o] = fmaf(xt.z, wf.z, acc[g][o]);
                acc[g][o] = fmaf(xt.w, wf.w, acc[g][o]);
            }
        }
    }

    // reduce over the 16 f-lanes on the VALU pipe (DPP butterflies)
#pragma unroll
    for (int g = 0; g < 4; ++g)
#pragma unroll
        for (int o = 0; o < OUT_N; ++o) acc[g][o] = red16(acc[g][o]);

    if (l16 == 0) {
#pragma unroll
        for (int g = 0; g < 4; ++g) {
            float* Cr = C + (size_t)(row0 + g) * OUT_N;   // 40 B stride: 8-aligned
#pragma unroll
            for (int p = 0; p < 5; ++p) {
                f2 s;
                s.x = acc[g][2 * p]     + bias[2 * p];
                s.y = acc[g][2 * p + 1] + bias[2 * p + 1];
                *(f2*)&Cr[2 * p] = s;
            }
        }
    }
}

// Phase 2: one thread per (b, o); IF-neuron scan over t.
__global__ __launch_bounds__(256)
void snn_scan(const float* __restrict__ C, float* __restrict__ out) {
    const int idx = blockIdx.x * 256 + threadIdx.x;   // b*OUT_N + o
    if (idx >= BATCH * OUT_N) return;
    float v = 0.0f;
    float cnt = 0.0f;
#pragma unroll
    for (int t = 0; t < T_STEPS; ++t) {
        v += C[(size_t)t * BATCH * OUT_N + idx];
        if (v >= 1.0f) { cnt += 1.0f; v = 0.0f; }
    }
    out[idx] = cnt * (1.0f / 64.0f);
}

extern "C" void kernel_launch(void* const* d_in, const int* in_sizes, int n_in,
                              void* d_out, int out_size, void* d_ws, size_t ws_size,
                              hipStream_t stream) {
    const float* x    = (const float*)d_in[0];   // [64, 2048, 784] f32
    const float* W    = (const float*)d_in[1];   // [10, 784] f32
    const float* bias = (const float*)d_in[2];   // [10] f32
    float* out = (float*)d_out;                  // [2048, 10] f32
    float* C   = (float*)d_ws;                   // [131072, 10] f32 scratch

    snn_gemm<<<dim3(ROWS / 64), dim3(256), 0, stream>>>(x, W, bias, C);
    snn_scan<<<dim3((BATCH * OUT_N + 255) / 256), dim3(256), 0, stream>>>(C, out);
}